// Round 13
// baseline (298.588 us; speedup 1.0000x reference)
//
#include <hip/hip_runtime.h>
#include <math.h>

#define TT 512
#define GG 3
#define HH 32
#define DD 128

typedef _Float16 half8 __attribute__((ext_vector_type(8)));
typedef float f32x4 __attribute__((ext_vector_type(4)));

__device__ __forceinline__ float fast_tanh(float x) {
  float e = __expf(2.0f * x);
  return 1.0f - 2.0f * __builtin_amdgcn_rcpf(1.0f + e);
}

// 16-seq group per 512-thread block, EIGHT waves: wave (T=wv>>2, P=wv&3) owns
// j-tile T and C-register P (one j per lane). Per wave per step: 1 b128
// broadcast h-read, 3 redundant MFMAs, ONE j x 3 gates = 6 transcendentals
// (trans chain was the bottleneck: 12@r12, 24@r5, 48@r3), 1 ds_write_b16,
// 1 barrier. 3072 waves = 3/SIMD: the trans pipe and LDS latency now overlap
// across groups.
__global__ __launch_bounds__(512) void gru_scan_mfma8(
    const float* __restrict__ x, const float* __restrict__ W_ih,
    const float* __restrict__ W_hh, const float* __restrict__ b_ih,
    const float* __restrict__ b_hh, float* __restrict__ hout, int B) {
  const int tid = threadIdx.x;
  const int wv = tid >> 6;
  const int lane = tid & 63;
  const int col = lane & 15;   // seq for B/C; m-row for A
  const int grp = lane >> 4;   // k-block for A/B; row-group for C
  const int T = wv >> 2;       // j-tile
  const int P = wv & 3;        // C register owned by this wave
  const int nb = B / 16;
  const int g = blockIdx.x / nb;
  const int b0 = (blockIdx.x % nb) * 16;
  const float L2E = 1.44269504088896340736f;

  __shared__ float xlds[16][TT + 1];
  __shared__ uint32_t hbuf[2][16][20];

  // ---- x preload (one-time) ----
#pragma unroll 4
  for (int i = tid; i < 16 * TT; i += 512) {
    int s = i >> 9, t = i & (TT - 1);
    xlds[s][t] = x[((size_t)(b0 + s) * TT + t) * GG + g];
  }

  // ---- A fragments for j-tile T (pre-scaled for exp2) ----
  half8 Af[3];
  const float* Wg = W_hh + (size_t)g * 3 * HH * HH;
#pragma unroll
  for (int gam = 0; gam < 3; ++gam) {
    const float sc = (gam == 2) ? 2.0f * L2E : -L2E;
    const float* src = Wg + (size_t)(gam * 32 + T * 16 + col) * HH + grp * 8;
    half8 a;
#pragma unroll
    for (int i = 0; i < 8; ++i) a[i] = (_Float16)(src[i] * sc);
    Af[gam] = a;
  }

  // ---- gate constants for this wave's single j = T*16 + grp*4 + P ----
  const int j = T * 16 + grp * 4 + P;
  const float wiR = W_ih[g * 96 + j] * (-L2E);
  const float wiZ = W_ih[g * 96 + 32 + j] * (-L2E);
  const float wiN = W_ih[g * 96 + 64 + j] * (2.0f * L2E);
  const float bR = (b_ih[g * 96 + j] + b_hh[g * 96 + j]) * (-L2E);
  const float bZ = (b_ih[g * 96 + 32 + j] + b_hh[g * 96 + 32 + j]) * (-L2E);
  const float bN = b_ih[g * 96 + 64 + j] * (2.0f * L2E);
  const float bHN = b_hh[g * 96 + 64 + j] * (2.0f * L2E);

  float ho = 0.0f;
  if (tid < 320) ((uint32_t*)hbuf)[tid] = 0u;  // zero buf 0
  __syncthreads();

  const f32x4 zero = {0.f, 0.f, 0.f, 0.f};

#define GRU_STEP(SRC, DST, TC)                                                 \
  {                                                                            \
    float xv = xlds[col][TC];                                                  \
    half8 Bf = *(const half8*)&hbuf[SRC][col][grp * 4];                        \
    f32x4 Cr = __builtin_amdgcn_mfma_f32_16x16x32_f16(Af[0], Bf, zero, 0, 0, 0); \
    f32x4 Cz = __builtin_amdgcn_mfma_f32_16x16x32_f16(Af[1], Bf, zero, 0, 0, 0); \
    f32x4 Cn = __builtin_amdgcn_mfma_f32_16x16x32_f16(Af[2], Bf, zero, 0, 0, 0); \
    float cr = (P & 2) ? ((P & 1) ? Cr[3] : Cr[2]) : ((P & 1) ? Cr[1] : Cr[0]); \
    float cz = (P & 2) ? ((P & 1) ? Cz[3] : Cz[2]) : ((P & 1) ? Cz[1] : Cz[0]); \
    float cn = (P & 2) ? ((P & 1) ? Cn[3] : Cn[2]) : ((P & 1) ? Cn[1] : Cn[0]); \
    float pr = cr + fmaf(xv, wiR, bR);                                         \
    float rr = __builtin_amdgcn_rcpf(1.0f + __builtin_amdgcn_exp2f(pr));       \
    float pz = cz + fmaf(xv, wiZ, bZ);                                         \
    float zz = __builtin_amdgcn_rcpf(1.0f + __builtin_amdgcn_exp2f(pz));       \
    float pn = fmaf(rr, cn + bHN, fmaf(xv, wiN, bN));                          \
    float u = __builtin_amdgcn_rcpf(1.0f + __builtin_amdgcn_exp2f(pn));        \
    float nn = fmaf(-2.0f, u, 1.0f);                                           \
    ho = fmaf(zz, ho - nn, nn);                                                \
    ((__fp16*)&hbuf[DST][col][0])[j] = (__fp16)ho;                             \
    __syncthreads();                                                           \
  }

#pragma unroll 1
  for (int t = 0; t < TT; t += 2) {
    GRU_STEP(0, 1, t)
    GRU_STEP(1, 0, t + 1)
  }
#undef GRU_STEP

  hout[((size_t)(b0 + col) * GG + g) * HH + j] = ho;
}

// One block per b: query -> scores -> softmax -> weighted rep -> out row,
// then broadcast-write the row across all T positions (coalesced float4).
__global__ __launch_bounds__(256) void epilogue(
    const float* __restrict__ ctx, const float* __restrict__ hf,
    const float* __restrict__ Wq, const float* __restrict__ bq,
    const float* __restrict__ Ws, const float* __restrict__ bs,
    const float* __restrict__ Wo, const float* __restrict__ bo,
    const float* __restrict__ logT, float* __restrict__ out, int B) {
  const int b = blockIdx.x;
  const int tid = threadIdx.x;
  __shared__ float sc[DD];
  __shared__ float sw[HH];
  __shared__ float srow[DD];
  if (tid < DD) sc[tid] = ctx[(size_t)b * DD + tid];
  __syncthreads();
  if (tid < HH) {
    float q = bq[tid];
#pragma unroll 4
    for (int d = 0; d < DD; ++d) q = fmaf(sc[d], Wq[d * HH + tid], q);
    float h0 = hf[((size_t)b * 3 + 0) * HH + tid];
    float h1 = hf[((size_t)b * 3 + 1) * HH + tid];
    float h2 = hf[((size_t)b * 3 + 2) * HH + tid];
    float wsv = Ws[tid];
    float s0 = fast_tanh(h0 + q) * wsv;
    float s1 = fast_tanh(h1 + q) * wsv;
    float s2 = fast_tanh(h2 + q) * wsv;
#pragma unroll
    for (int off = 16; off >= 1; off >>= 1) {
      s0 += __shfl_xor(s0, off, 32);
      s1 += __shfl_xor(s1, off, 32);
      s2 += __shfl_xor(s2, off, 32);
    }
    float bsv = bs[0];
    float tmp = fmaxf(__expf(logT[0]), 0.1f);
    float inv = 1.0f / tmp;
    s0 = (s0 + bsv) * inv; s1 = (s1 + bsv) * inv; s2 = (s2 + bsv) * inv;
    float m = fmaxf(s0, fmaxf(s1, s2));
    float e0 = __expf(s0 - m), e1 = __expf(s1 - m), e2 = __expf(s2 - m);
    float den = 1.0f / (e0 + e1 + e2);
    float a0 = e0 * den, a1 = e1 * den, a2 = e2 * den;
    sw[tid] = a0 * h0 + a1 * h1 + a2 * h2;
    if (tid == 0) {
      size_t aoff = (size_t)B * TT * DD + (size_t)b * 3;
      out[aoff] = a0; out[aoff + 1] = a1; out[aoff + 2] = a2;
    }
  }
  __syncthreads();
  if (tid < DD) {
    float o = bo[tid];
#pragma unroll
    for (int h = 0; h < HH; ++h) o = fmaf(sw[h], Wo[h * DD + tid], o);
    srow[tid] = o;
  }
  __syncthreads();
  const float4 v = *(const float4*)&srow[(tid & 31) * 4];
  float4* o4 = (float4*)out + (size_t)b * (TT * DD / 4);
#pragma unroll 4
  for (int i = tid; i < TT * DD / 4; i += 256) {
    o4[i] = v;
  }
}

extern "C" void kernel_launch(void* const* d_in, const int* in_sizes, int n_in,
                              void* d_out, int out_size, void* d_ws, size_t ws_size,
                              hipStream_t stream) {
  const float* x    = (const float*)d_in[0];
  const float* ctx  = (const float*)d_in[1];
  const float* W_ih = (const float*)d_in[2];
  const float* W_hh = (const float*)d_in[3];
  const float* b_ih = (const float*)d_in[4];
  const float* b_hh = (const float*)d_in[5];
  const float* Wq   = (const float*)d_in[6];
  const float* bq   = (const float*)d_in[7];
  const float* Ws   = (const float*)d_in[8];
  const float* bs   = (const float*)d_in[9];
  const float* Wo   = (const float*)d_in[10];
  const float* bo   = (const float*)d_in[11];
  const float* logT = (const float*)d_in[12];
  float* out = (float*)d_out;
  const int B = in_sizes[0] / (TT * GG);

  float* hf = (float*)d_ws;  // B*G*H floats

  dim3 g1((B / 16) * GG);
  gru_scan_mfma8<<<g1, 512, 0, stream>>>(x, W_ih, W_hh, b_ih, b_hh, hf, B);
  epilogue<<<B, 256, 0, stream>>>(ctx, hf, Wq, bq, Ws, bs, Wo, bo, logT, out, B);
}